// Round 8
// baseline (1124.921 us; speedup 1.0000x reference)
//
#include <hip/hip_runtime.h>
#include <math.h>

#define D_MODEL 1024
#define NHEADS  16
#define DK      64
#define BB      2
#define SS      2048
#define MT      (BB*SS)   // 4096 rows

// ---------------------------------------------------------------------------
// RoPE table: tab[pos][i] = cos(pos*freq_i), tab[pos][32+i] = sin(pos*freq_i)
// freq_i = 10000^(-2i/64), i in [0,32), pos in [0,2048)
// ---------------------------------------------------------------------------
__global__ void rope_table_kernel(float* __restrict__ tab) {
    int idx = blockIdx.x * 256 + threadIdx.x;   // 2048*32 = 65536 threads
    int p = idx >> 5;
    int i = idx & 31;
    float freq = powf(10000.0f, -(float)(2 * i) / 64.0f);
    float ang = (float)p * freq;
    tab[p * 64 + i]      = cosf(ang);
    tab[p * 64 + 32 + i] = sinf(ang);
}

// ---------------------------------------------------------------------------
// GEMM: C[m][n] = sum_k A[m][k] * W[n][k]   (A: M x 1024 row-major,
// W: 1024 x 1024 row-major [n][k])  M=4096, N=1024, K=1024
// Tile: 128(M) x 64(N), BK=16, 256 threads, 8x4 micro-tile per thread.
// blockIdx.z selects (W, C) pair so Q/K/V run in one launch.
// ---------------------------------------------------------------------------
__global__ __launch_bounds__(256) void gemm_awt(
    const float* __restrict__ A,
    const float* __restrict__ W0, const float* __restrict__ W1, const float* __restrict__ W2,
    float* __restrict__ C0, float* __restrict__ C1, float* __restrict__ C2)
{
    const float* W;
    float* C;
    if (blockIdx.z == 0)      { W = W0; C = C0; }
    else if (blockIdx.z == 1) { W = W1; C = C1; }
    else                      { W = W2; C = C2; }

    __shared__ float As[16][132];   // k-major, padded: row stride 132*4=528B (16B-mult)
    __shared__ float Bs[16][68];    // k-major, padded: 68*4=272B

    int tid = threadIdx.x;
    int tx = tid & 15, ty = tid >> 4;
    int m0 = blockIdx.y * 128;
    int n0 = blockIdx.x * 64;

    int ar = tid >> 2;          // 0..63
    int ac = (tid & 3) << 2;    // 0,4,8,12
    const float* Ap = A + (size_t)(m0 + ar) * D_MODEL + ac;
    const float* Wp = W + (size_t)(n0 + ar) * D_MODEL + ac;

    float acc[8][4];
#pragma unroll
    for (int i = 0; i < 8; i++)
#pragma unroll
        for (int j = 0; j < 4; j++) acc[i][j] = 0.0f;

    for (int k0 = 0; k0 < D_MODEL; k0 += 16) {
        float4 a0 = *(const float4*)(Ap + k0);
        float4 a1 = *(const float4*)(Ap + (size_t)64 * D_MODEL + k0);
        float4 b0 = *(const float4*)(Wp + k0);
        __syncthreads();   // previous compute finished before overwrite
        As[ac + 0][ar] = a0.x; As[ac + 1][ar] = a0.y; As[ac + 2][ar] = a0.z; As[ac + 3][ar] = a0.w;
        As[ac + 0][ar + 64] = a1.x; As[ac + 1][ar + 64] = a1.y; As[ac + 2][ar + 64] = a1.z; As[ac + 3][ar + 64] = a1.w;
        Bs[ac + 0][ar] = b0.x; Bs[ac + 1][ar] = b0.y; Bs[ac + 2][ar] = b0.z; Bs[ac + 3][ar] = b0.w;
        __syncthreads();
#pragma unroll
        for (int kk = 0; kk < 16; ++kk) {
            float4 av0 = *(const float4*)&As[kk][ty * 8];
            float4 av1 = *(const float4*)&As[kk][ty * 8 + 4];
            float4 bv  = *(const float4*)&Bs[kk][tx * 4];
            float a[8] = {av0.x, av0.y, av0.z, av0.w, av1.x, av1.y, av1.z, av1.w};
            float b[4] = {bv.x, bv.y, bv.z, bv.w};
#pragma unroll
            for (int i = 0; i < 8; i++)
#pragma unroll
                for (int j = 0; j < 4; j++)
                    acc[i][j] = fmaf(a[i], b[j], acc[i][j]);
        }
    }

#pragma unroll
    for (int i = 0; i < 8; i++) {
        float4 o = make_float4(acc[i][0], acc[i][1], acc[i][2], acc[i][3]);
        *(float4*)(C + (size_t)(m0 + ty * 8 + i) * D_MODEL + n0 + tx * 4) = o;
    }
}

// ---------------------------------------------------------------------------
// RoPE apply, in place on Q (grid.y=0) and K (grid.y=1).
// idx bits: i(5) | h(4) | t(11) | b(1)  -> 2^21 pairs per tensor
// element offset = ((b*S+t)*16+h)*64 + 2*i = (idx>>5)*64 + 2*(idx&31)
// ---------------------------------------------------------------------------
__global__ void rope_apply_kernel(float* __restrict__ Qp, float* __restrict__ Kp,
                                  const int* __restrict__ pos, const float* __restrict__ tab)
{
    int idx = blockIdx.x * 256 + threadIdx.x;
    float* base = blockIdx.y ? Kp : Qp;
    int i = idx & 31;
    int row = idx >> 5;                 // (b*S+t)*16 + h
    float* ptr = base + (size_t)row * 64 + 2 * i;
    int p = pos[idx >> 9];              // b*S + t
    float c  = tab[p * 64 + i];
    float sn = tab[p * 64 + 32 + i];
    float2 v = *(float2*)ptr;
    float2 r;
    r.x = v.x * c - v.y * sn;
    r.y = v.x * sn + v.y * c;
    *(float2*)ptr = r;
}

// ---------------------------------------------------------------------------
// Causal flash attention, fp32. Q/K/V layout: [b][t][h][d] flat (stride 1024).
// Block: 256 threads, BQ=BKV=64, 4x4 register tile per thread.
// LDS: Qs[d][q] 16K, KP[d][k]->reused as P[k][q] 16K, Vs[k][d] 16K.
// grid: (S/64=32 qtiles, B*H=32)
// ---------------------------------------------------------------------------
__global__ __launch_bounds__(256) void attn_fp32_kernel(
    const float* __restrict__ Q, const float* __restrict__ K,
    const float* __restrict__ V, float* __restrict__ O)
{
    __shared__ float Qs[64][64];   // [d][q]
    __shared__ float KP[64][64];   // [d][k] for K, then [k][q] for P
    __shared__ float Vs[64][64];   // [k][d]

    int tid = threadIdx.x;
    int tx = tid & 15, ty = tid >> 4;
    int qt = blockIdx.x;
    int bh = blockIdx.y;
    int b = bh >> 4, h = bh & 15;

    const float* Qb = Q + (size_t)b * SS * D_MODEL + h * DK;
    const float* Kb = K + (size_t)b * SS * D_MODEL + h * DK;
    const float* Vb = V + (size_t)b * SS * D_MODEL + h * DK;
    int q0 = qt * 64;

    // load Q tile (d-major in LDS)
#pragma unroll
    for (int u = 0; u < 4; ++u) {
        int f = u * 256 + tid;
        int r = f >> 4, cv = (f & 15) << 2;
        float4 qv = *(const float4*)(Qb + (size_t)(q0 + r) * D_MODEL + cv);
        Qs[cv + 0][r] = qv.x; Qs[cv + 1][r] = qv.y; Qs[cv + 2][r] = qv.z; Qs[cv + 3][r] = qv.w;
    }

    float m[4], l[4], o[4][4];
#pragma unroll
    for (int i = 0; i < 4; i++) {
        m[i] = -1e30f; l[i] = 0.0f;
#pragma unroll
        for (int j = 0; j < 4; j++) o[i][j] = 0.0f;
    }

    for (int kt = 0; kt <= qt; ++kt) {
        int k0 = kt * 64;
        float4 kv[4], vv[4];
#pragma unroll
        for (int u = 0; u < 4; ++u) {
            int f = u * 256 + tid;
            int r = f >> 4, cv = (f & 15) << 2;
            kv[u] = *(const float4*)(Kb + (size_t)(k0 + r) * D_MODEL + cv);
            vv[u] = *(const float4*)(Vb + (size_t)(k0 + r) * D_MODEL + cv);
        }
        __syncthreads();   // previous iteration's LDS reads done (also covers Q-tile writes, iter 0)
#pragma unroll
        for (int u = 0; u < 4; ++u) {
            int f = u * 256 + tid;
            int r = f >> 4, cv = (f & 15) << 2;
            KP[cv + 0][r] = kv[u].x; KP[cv + 1][r] = kv[u].y; KP[cv + 2][r] = kv[u].z; KP[cv + 3][r] = kv[u].w;
            *(float4*)&Vs[r][cv] = vv[u];
        }
        __syncthreads();

        // S = Q K^T (64 x 64), thread owns rows ty*4..+3, cols tx*4..+3
        float s[4][4];
#pragma unroll
        for (int i = 0; i < 4; i++)
#pragma unroll
            for (int j = 0; j < 4; j++) s[i][j] = 0.0f;
#pragma unroll 8
        for (int d = 0; d < 64; ++d) {
            float4 qa = *(const float4*)&Qs[d][ty * 4];
            float4 ka = *(const float4*)&KP[d][tx * 4];
            float qv[4] = {qa.x, qa.y, qa.z, qa.w};
            float kk2[4] = {ka.x, ka.y, ka.z, ka.w};
#pragma unroll
            for (int i = 0; i < 4; i++)
#pragma unroll
                for (int j = 0; j < 4; j++)
                    s[i][j] = fmaf(qv[i], kk2[j], s[i][j]);
        }

        const float sc = 0.125f;   // 1/sqrt(64)
        if (kt == qt) {
#pragma unroll
            for (int i = 0; i < 4; i++)
#pragma unroll
                for (int j = 0; j < 4; j++)
                    s[i][j] = (tx * 4 + j <= ty * 4 + i) ? s[i][j] * sc : -1e30f;
        } else {
#pragma unroll
            for (int i = 0; i < 4; i++)
#pragma unroll
                for (int j = 0; j < 4; j++)
                    s[i][j] *= sc;
        }

        // online softmax (reduce across the 16-lane tx group)
        float p[4][4];
#pragma unroll
        for (int i = 0; i < 4; i++) {
            float rm = fmaxf(fmaxf(s[i][0], s[i][1]), fmaxf(s[i][2], s[i][3]));
            rm = fmaxf(rm, __shfl_xor(rm, 1));
            rm = fmaxf(rm, __shfl_xor(rm, 2));
            rm = fmaxf(rm, __shfl_xor(rm, 4));
            rm = fmaxf(rm, __shfl_xor(rm, 8));
            float nm = fmaxf(m[i], rm);
            float alpha = __expf(m[i] - nm);
            m[i] = nm;
            float rs = 0.0f;
#pragma unroll
            for (int j = 0; j < 4; j++) { p[i][j] = __expf(s[i][j] - nm); rs += p[i][j]; }
            rs += __shfl_xor(rs, 1);
            rs += __shfl_xor(rs, 2);
            rs += __shfl_xor(rs, 4);
            rs += __shfl_xor(rs, 8);
            l[i] = l[i] * alpha + rs;
#pragma unroll
            for (int j = 0; j < 4; j++) o[i][j] *= alpha;
        }

        __syncthreads();   // all S-phase reads of KP done before P overwrite
#pragma unroll
        for (int j = 0; j < 4; j++) {
            float4 pv = make_float4(p[0][j], p[1][j], p[2][j], p[3][j]);
            *(float4*)&KP[tx * 4 + j][ty * 4] = pv;   // P[k][q]
        }
        __syncthreads();

        // O += P V  (thread owns q-rows ty*4..+3, d-cols tx*4..+3)
#pragma unroll 8
        for (int k = 0; k < 64; ++k) {
            float4 pa = *(const float4*)&KP[k][ty * 4];
            float4 va = *(const float4*)&Vs[k][tx * 4];
            float pv2[4] = {pa.x, pa.y, pa.z, pa.w};
            float vv2[4] = {va.x, va.y, va.z, va.w};
#pragma unroll
            for (int i = 0; i < 4; i++)
#pragma unroll
                for (int j = 0; j < 4; j++)
                    o[i][j] = fmaf(pv2[i], vv2[j], o[i][j]);
        }
    }

    float* Ob = O + (size_t)b * SS * D_MODEL + h * DK;
#pragma unroll
    for (int i = 0; i < 4; i++) {
        float inv = 1.0f / l[i];
        float4 ov = make_float4(o[i][0] * inv, o[i][1] * inv, o[i][2] * inv, o[i][3] * inv);
        *(float4*)(Ob + (size_t)(q0 + ty * 4 + i) * D_MODEL + tx * 4) = ov;
    }
}

// ---------------------------------------------------------------------------
extern "C" void kernel_launch(void* const* d_in, const int* in_sizes, int n_in,
                              void* d_out, int out_size, void* d_ws, size_t ws_size,
                              hipStream_t stream)
{
    const float* x    = (const float*)d_in[0];
    const int*   tpos = (const int*)d_in[1];
    const float* Wq   = (const float*)d_in[2];
    const float* Wk   = (const float*)d_in[3];
    const float* Wv   = (const float*)d_in[4];
    const float* Wo   = (const float*)d_in[5];
    float* out = (float*)d_out;

    float* ws = (float*)d_ws;
    float* q   = ws;                               // 4M floats
    float* k   = q + (size_t)MT * D_MODEL;         // 4M
    float* v   = k + (size_t)MT * D_MODEL;         // 4M
    float* o   = v + (size_t)MT * D_MODEL;         // 4M
    float* tab = o + (size_t)MT * D_MODEL;         // 2048*64 floats

    // 1. RoPE cos/sin table
    hipLaunchKernelGGL(rope_table_kernel, dim3(256), dim3(256), 0, stream, tab);
    // 2. Q/K/V projections (one fused launch, z selects weight/output)
    hipLaunchKernelGGL(gemm_awt, dim3(16, 32, 3), dim3(256), 0, stream,
                       x, Wq, Wk, Wv, q, k, v);
    // 3. RoPE on Q and K in place
    hipLaunchKernelGGL(rope_apply_kernel, dim3(8192, 2), dim3(256), 0, stream,
                       q, k, tpos, tab);
    // 4. causal flash attention
    hipLaunchKernelGGL(attn_fp32_kernel, dim3(32, 32), dim3(256), 0, stream,
                       q, k, v, o);
    // 5. output projection
    hipLaunchKernelGGL(gemm_awt, dim3(16, 32, 1), dim3(256), 0, stream,
                       o, Wo, Wo, Wo, out, out, out);
}

// Round 9
// 927.521 us; speedup vs baseline: 1.2128x; 1.2128x over previous
//
#include <hip/hip_runtime.h>
#include <math.h>

#define D_MODEL 1024
#define NHEADS  16
#define DK      64
#define BB      2
#define SS      2048
#define MT      (BB*SS)   // 4096 rows

// ---------------------------------------------------------------------------
// RoPE table: tab[pos][i] = cos(pos*freq_i), tab[pos][32+i] = sin(pos*freq_i)
// ---------------------------------------------------------------------------
__global__ void rope_table_kernel(float* __restrict__ tab) {
    int idx = blockIdx.x * 256 + threadIdx.x;   // 2048*32 = 65536 threads
    int p = idx >> 5;
    int i = idx & 31;
    float freq = powf(10000.0f, -(float)(2 * i) / 64.0f);
    float ang = (float)p * freq;
    tab[p * 64 + i]      = cosf(ang);
    tab[p * 64 + 32 + i] = sinf(ang);
}

// ---------------------------------------------------------------------------
// GEMM: C[m][n] = sum_k A[m][k] * W[n][k]  (unchanged from round-8 anchor)
// ---------------------------------------------------------------------------
__global__ __launch_bounds__(256) void gemm_awt(
    const float* __restrict__ A,
    const float* __restrict__ W0, const float* __restrict__ W1, const float* __restrict__ W2,
    float* __restrict__ C0, float* __restrict__ C1, float* __restrict__ C2)
{
    const float* W;
    float* C;
    if (blockIdx.z == 0)      { W = W0; C = C0; }
    else if (blockIdx.z == 1) { W = W1; C = C1; }
    else                      { W = W2; C = C2; }

    __shared__ float As[16][132];
    __shared__ float Bs[16][68];

    int tid = threadIdx.x;
    int tx = tid & 15, ty = tid >> 4;
    int m0 = blockIdx.y * 128;
    int n0 = blockIdx.x * 64;

    int ar = tid >> 2;
    int ac = (tid & 3) << 2;
    const float* Ap = A + (size_t)(m0 + ar) * D_MODEL + ac;
    const float* Wp = W + (size_t)(n0 + ar) * D_MODEL + ac;

    float acc[8][4];
#pragma unroll
    for (int i = 0; i < 8; i++)
#pragma unroll
        for (int j = 0; j < 4; j++) acc[i][j] = 0.0f;

    for (int k0 = 0; k0 < D_MODEL; k0 += 16) {
        float4 a0 = *(const float4*)(Ap + k0);
        float4 a1 = *(const float4*)(Ap + (size_t)64 * D_MODEL + k0);
        float4 b0 = *(const float4*)(Wp + k0);
        __syncthreads();
        As[ac + 0][ar] = a0.x; As[ac + 1][ar] = a0.y; As[ac + 2][ar] = a0.z; As[ac + 3][ar] = a0.w;
        As[ac + 0][ar + 64] = a1.x; As[ac + 1][ar + 64] = a1.y; As[ac + 2][ar + 64] = a1.z; As[ac + 3][ar + 64] = a1.w;
        Bs[ac + 0][ar] = b0.x; Bs[ac + 1][ar] = b0.y; Bs[ac + 2][ar] = b0.z; Bs[ac + 3][ar] = b0.w;
        __syncthreads();
#pragma unroll
        for (int kk = 0; kk < 16; ++kk) {
            float4 av0 = *(const float4*)&As[kk][ty * 8];
            float4 av1 = *(const float4*)&As[kk][ty * 8 + 4];
            float4 bv  = *(const float4*)&Bs[kk][tx * 4];
            float a[8] = {av0.x, av0.y, av0.z, av0.w, av1.x, av1.y, av1.z, av1.w};
            float b[4] = {bv.x, bv.y, bv.z, bv.w};
#pragma unroll
            for (int i = 0; i < 8; i++)
#pragma unroll
                for (int j = 0; j < 4; j++)
                    acc[i][j] = fmaf(a[i], b[j], acc[i][j]);
        }
    }

#pragma unroll
    for (int i = 0; i < 8; i++) {
        float4 o = make_float4(acc[i][0], acc[i][1], acc[i][2], acc[i][3]);
        *(float4*)(C + (size_t)(m0 + ty * 8 + i) * D_MODEL + n0 + tx * 4) = o;
    }
}

// ---------------------------------------------------------------------------
// RoPE apply (unchanged)
// ---------------------------------------------------------------------------
__global__ void rope_apply_kernel(float* __restrict__ Qp, float* __restrict__ Kp,
                                  const int* __restrict__ pos, const float* __restrict__ tab)
{
    int idx = blockIdx.x * 256 + threadIdx.x;
    float* base = blockIdx.y ? Kp : Qp;
    int i = idx & 31;
    int row = idx >> 5;
    float* ptr = base + (size_t)row * 64 + 2 * i;
    int p = pos[idx >> 9];
    float c  = tab[p * 64 + i];
    float sn = tab[p * 64 + 32 + i];
    float2 v = *(float2*)ptr;
    float2 r;
    r.x = v.x * c - v.y * sn;
    r.y = v.x * sn + v.y * c;
    *(float2*)ptr = r;
}

// ---------------------------------------------------------------------------
// Causal flash attention v2, fp32.
// Balance: block handles q-tile PAIR (qt, 31-qt) -> exactly 33 kv-tiles/block.
// Grid (16,32) = 512 blocks = 2/CU, whole grid co-resident (zero tail).
// 512 threads (8 waves), 4q x 2k micro-tile; K/V prefetched into regs.
// LDS rows padded to 68 floats: reads conflict-free, writes ~8-way (was 16).
// KP buffer reused for P ([k][q]) between phases (stays under 64KB static).
// ---------------------------------------------------------------------------
__global__ __launch_bounds__(512) void attn_fp32_v2(
    const float* __restrict__ Q, const float* __restrict__ K,
    const float* __restrict__ V, float* __restrict__ O)
{
    __shared__ float Qs[64][68];   // [d][q]
    __shared__ float KP[64][68];   // [d][k] for K, then [k][q] for P
    __shared__ float Vs[64][68];   // [k][d]

    int tid = threadIdx.x;
    int tx = tid & 31;        // k (or d) group of 2
    int ty = tid >> 5;        // 0..15, q group of 4
    int bh = blockIdx.y;
    int b = bh >> 4, h = bh & 15;

    const float* Qb = Q + (size_t)b * SS * D_MODEL + h * DK;
    const float* Kb = K + (size_t)b * SS * D_MODEL + h * DK;
    const float* Vb = V + (size_t)b * SS * D_MODEL + h * DK;
    float* Ob = O + (size_t)b * SS * D_MODEL + h * DK;

    // staging map: 512 threads x 2 iters cover 64 rows x 16 float4-cols
    int sr = tid >> 4;          // 0..31
    int sc = (tid & 15) << 2;   // 0,4,...,60

#pragma unroll 1
    for (int half = 0; half < 2; ++half) {
        int qt = half ? (31 - blockIdx.x) : blockIdx.x;
        int q0 = qt * 64;

        // Q stage (visibility via barrier #1 of first tile)
#pragma unroll
        for (int u = 0; u < 2; ++u) {
            int r = u * 32 + sr;
            float4 qv = *(const float4*)(Qb + (size_t)(q0 + r) * D_MODEL + sc);
            Qs[sc + 0][r] = qv.x; Qs[sc + 1][r] = qv.y; Qs[sc + 2][r] = qv.z; Qs[sc + 3][r] = qv.w;
        }

        float m[4], l[4], o_[4][2];
#pragma unroll
        for (int i = 0; i < 4; i++) {
            m[i] = -1e30f; l[i] = 0.0f; o_[i][0] = 0.0f; o_[i][1] = 0.0f;
        }

        // prefetch kt=0
        float4 kv[2], vv[2];
#pragma unroll
        for (int u = 0; u < 2; ++u) {
            int r = u * 32 + sr;
            kv[u] = *(const float4*)(Kb + (size_t)r * D_MODEL + sc);
            vv[u] = *(const float4*)(Vb + (size_t)r * D_MODEL + sc);
        }

        for (int kt = 0; kt <= qt; ++kt) {
            __syncthreads();   // #1: prev tile's PV reads (Vs, KP-as-P) done; Q writes ordered
#pragma unroll
            for (int u = 0; u < 2; ++u) {
                int r = u * 32 + sr;
                KP[sc + 0][r] = kv[u].x; KP[sc + 1][r] = kv[u].y; KP[sc + 2][r] = kv[u].z; KP[sc + 3][r] = kv[u].w;
                *(float4*)&Vs[r][sc] = vv[u];
            }
            __syncthreads();   // #2: staging visible

            // prefetch next tile during compute
            if (kt < qt) {
                int k0n = (kt + 1) * 64;
#pragma unroll
                for (int u = 0; u < 2; ++u) {
                    int r = u * 32 + sr;
                    kv[u] = *(const float4*)(Kb + (size_t)(k0n + r) * D_MODEL + sc);
                    vv[u] = *(const float4*)(Vb + (size_t)(k0n + r) * D_MODEL + sc);
                }
            }

            // S = Q K^T: thread owns rows ty*4..+3, cols tx*2..+1
            float s[4][2];
#pragma unroll
            for (int i = 0; i < 4; i++) { s[i][0] = 0.0f; s[i][1] = 0.0f; }
#pragma unroll 8
            for (int d = 0; d < 64; ++d) {
                float4 qa = *(const float4*)&Qs[d][ty * 4];
                float2 ka = *(const float2*)&KP[d][tx * 2];
                float qv4[4] = {qa.x, qa.y, qa.z, qa.w};
#pragma unroll
                for (int i = 0; i < 4; i++) {
                    s[i][0] = fmaf(qv4[i], ka.x, s[i][0]);
                    s[i][1] = fmaf(qv4[i], ka.y, s[i][1]);
                }
            }

            const float sc2 = 0.125f;   // 1/sqrt(64)
            if (kt == qt) {
#pragma unroll
                for (int i = 0; i < 4; i++)
#pragma unroll
                    for (int j = 0; j < 2; j++)
                        s[i][j] = (tx * 2 + j <= ty * 4 + i) ? s[i][j] * sc2 : -1e30f;
            } else {
#pragma unroll
                for (int i = 0; i < 4; i++) { s[i][0] *= sc2; s[i][1] *= sc2; }
            }

            // online softmax over the 32-lane tx group
            float p[4][2];
#pragma unroll
            for (int i = 0; i < 4; i++) {
                float rm = fmaxf(s[i][0], s[i][1]);
                rm = fmaxf(rm, __shfl_xor(rm, 1));
                rm = fmaxf(rm, __shfl_xor(rm, 2));
                rm = fmaxf(rm, __shfl_xor(rm, 4));
                rm = fmaxf(rm, __shfl_xor(rm, 8));
                rm = fmaxf(rm, __shfl_xor(rm, 16));
                float nm = fmaxf(m[i], rm);
                float alpha = __expf(m[i] - nm);
                m[i] = nm;
                p[i][0] = __expf(s[i][0] - nm);
                p[i][1] = __expf(s[i][1] - nm);
                float rs = p[i][0] + p[i][1];
                rs += __shfl_xor(rs, 1);
                rs += __shfl_xor(rs, 2);
                rs += __shfl_xor(rs, 4);
                rs += __shfl_xor(rs, 8);
                rs += __shfl_xor(rs, 16);
                l[i] = l[i] * alpha + rs;
                o_[i][0] *= alpha; o_[i][1] *= alpha;
            }

            __syncthreads();   // #3: all S-phase reads of KP done
#pragma unroll
            for (int j = 0; j < 2; j++) {
                float4 pv = make_float4(p[0][j], p[1][j], p[2][j], p[3][j]);
                *(float4*)&KP[tx * 2 + j][ty * 4] = pv;   // P[k][q]
            }
            __syncthreads();   // #4: P visible

            // O += P V: thread owns q-rows ty*4..+3, d-cols tx*2..+1
#pragma unroll 8
            for (int k = 0; k < 64; ++k) {
                float4 pa = *(const float4*)&KP[k][ty * 4];
                float2 va = *(const float2*)&Vs[k][tx * 2];
                float pv4[4] = {pa.x, pa.y, pa.z, pa.w};
#pragma unroll
                for (int i = 0; i < 4; i++) {
                    o_[i][0] = fmaf(pv4[i], va.x, o_[i][0]);
                    o_[i][1] = fmaf(pv4[i], va.y, o_[i][1]);
                }
            }
        }

        // epilogue
#pragma unroll
        for (int i = 0; i < 4; i++) {
            float inv = 1.0f / l[i];
            float2 ov = make_float2(o_[i][0] * inv, o_[i][1] * inv);
            *(float2*)(Ob + (size_t)(q0 + ty * 4 + i) * D_MODEL + tx * 2) = ov;
        }
    }
}

// ---------------------------------------------------------------------------
extern "C" void kernel_launch(void* const* d_in, const int* in_sizes, int n_in,
                              void* d_out, int out_size, void* d_ws, size_t ws_size,
                              hipStream_t stream)
{
    const float* x    = (const float*)d_in[0];
    const int*   tpos = (const int*)d_in[1];
    const float* Wq   = (const float*)d_in[2];
    const float* Wk   = (const float*)d_in[3];
    const float* Wv   = (const float*)d_in[4];
    const float* Wo   = (const float*)d_in[5];
    float* out = (float*)d_out;

    float* ws = (float*)d_ws;
    float* q   = ws;                               // 4M floats
    float* k   = q + (size_t)MT * D_MODEL;         // 4M
    float* v   = k + (size_t)MT * D_MODEL;         // 4M
    float* o   = v + (size_t)MT * D_MODEL;         // 4M
    float* tab = o + (size_t)MT * D_MODEL;         // 2048*64 floats

    // 1. RoPE cos/sin table
    hipLaunchKernelGGL(rope_table_kernel, dim3(256), dim3(256), 0, stream, tab);
    // 2. Q/K/V projections
    hipLaunchKernelGGL(gemm_awt, dim3(16, 32, 3), dim3(256), 0, stream,
                       x, Wq, Wk, Wv, q, k, v);
    // 3. RoPE on Q and K in place
    hipLaunchKernelGGL(rope_apply_kernel, dim3(8192, 2), dim3(256), 0, stream,
                       q, k, tpos, tab);
    // 4. causal flash attention v2 (paired q-tiles, 512 threads)
    hipLaunchKernelGGL(attn_fp32_v2, dim3(16, 32), dim3(512), 0, stream,
                       q, k, v, o);
    // 5. output projection
    hipLaunchKernelGGL(gemm_awt, dim3(16, 32, 1), dim3(256), 0, stream,
                       o, Wo, Wo, Wo, out, out, out);
}

// Round 10
// 893.781 us; speedup vs baseline: 1.2586x; 1.0377x over previous
//
#include <hip/hip_runtime.h>
#include <math.h>

#define D_MODEL 1024
#define NHEADS  16
#define DK      64
#define BB      2
#define SS      2048
#define MT      (BB*SS)   // 4096 rows

// ---------------------------------------------------------------------------
// RoPE table: tab[pos][i] = cos(pos*freq_i), tab[pos][32+i] = sin(pos*freq_i)
// ---------------------------------------------------------------------------
__global__ void rope_table_kernel(float* __restrict__ tab) {
    int idx = blockIdx.x * 256 + threadIdx.x;   // 2048*32 = 65536 threads
    int p = idx >> 5;
    int i = idx & 31;
    float freq = powf(10000.0f, -(float)(2 * i) / 64.0f);
    float ang = (float)p * freq;
    tab[p * 64 + i]      = cosf(ang);
    tab[p * 64 + 32 + i] = sinf(ang);
}

// ---------------------------------------------------------------------------
// GEMM: C[m][n] = sum_k A[m][k] * W[n][k]  (unchanged from round-8 anchor)
// ---------------------------------------------------------------------------
__global__ __launch_bounds__(256) void gemm_awt(
    const float* __restrict__ A,
    const float* __restrict__ W0, const float* __restrict__ W1, const float* __restrict__ W2,
    float* __restrict__ C0, float* __restrict__ C1, float* __restrict__ C2)
{
    const float* W;
    float* C;
    if (blockIdx.z == 0)      { W = W0; C = C0; }
    else if (blockIdx.z == 1) { W = W1; C = C1; }
    else                      { W = W2; C = C2; }

    __shared__ float As[16][132];
    __shared__ float Bs[16][68];

    int tid = threadIdx.x;
    int tx = tid & 15, ty = tid >> 4;
    int m0 = blockIdx.y * 128;
    int n0 = blockIdx.x * 64;

    int ar = tid >> 2;
    int ac = (tid & 3) << 2;
    const float* Ap = A + (size_t)(m0 + ar) * D_MODEL + ac;
    const float* Wp = W + (size_t)(n0 + ar) * D_MODEL + ac;

    float acc[8][4];
#pragma unroll
    for (int i = 0; i < 8; i++)
#pragma unroll
        for (int j = 0; j < 4; j++) acc[i][j] = 0.0f;

    for (int k0 = 0; k0 < D_MODEL; k0 += 16) {
        float4 a0 = *(const float4*)(Ap + k0);
        float4 a1 = *(const float4*)(Ap + (size_t)64 * D_MODEL + k0);
        float4 b0 = *(const float4*)(Wp + k0);
        __syncthreads();
        As[ac + 0][ar] = a0.x; As[ac + 1][ar] = a0.y; As[ac + 2][ar] = a0.z; As[ac + 3][ar] = a0.w;
        As[ac + 0][ar + 64] = a1.x; As[ac + 1][ar + 64] = a1.y; As[ac + 2][ar + 64] = a1.z; As[ac + 3][ar + 64] = a1.w;
        Bs[ac + 0][ar] = b0.x; Bs[ac + 1][ar] = b0.y; Bs[ac + 2][ar] = b0.z; Bs[ac + 3][ar] = b0.w;
        __syncthreads();
#pragma unroll
        for (int kk = 0; kk < 16; ++kk) {
            float4 av0 = *(const float4*)&As[kk][ty * 8];
            float4 av1 = *(const float4*)&As[kk][ty * 8 + 4];
            float4 bv  = *(const float4*)&Bs[kk][tx * 4];
            float a[8] = {av0.x, av0.y, av0.z, av0.w, av1.x, av1.y, av1.z, av1.w};
            float b[4] = {bv.x, bv.y, bv.z, bv.w};
#pragma unroll
            for (int i = 0; i < 8; i++)
#pragma unroll
                for (int j = 0; j < 4; j++)
                    acc[i][j] = fmaf(a[i], b[j], acc[i][j]);
        }
    }

#pragma unroll
    for (int i = 0; i < 8; i++) {
        float4 o = make_float4(acc[i][0], acc[i][1], acc[i][2], acc[i][3]);
        *(float4*)(C + (size_t)(m0 + ty * 8 + i) * D_MODEL + n0 + tx * 4) = o;
    }
}

// ---------------------------------------------------------------------------
// RoPE apply (unchanged)
// ---------------------------------------------------------------------------
__global__ void rope_apply_kernel(float* __restrict__ Qp, float* __restrict__ Kp,
                                  const int* __restrict__ pos, const float* __restrict__ tab)
{
    int idx = blockIdx.x * 256 + threadIdx.x;
    float* base = blockIdx.y ? Kp : Qp;
    int i = idx & 31;
    int row = idx >> 5;
    float* ptr = base + (size_t)row * 64 + 2 * i;
    int p = pos[idx >> 9];
    float c  = tab[p * 64 + i];
    float sn = tab[p * 64 + 32 + i];
    float2 v = *(float2*)ptr;
    float2 r;
    r.x = v.x * c - v.y * sn;
    r.y = v.x * sn + v.y * c;
    *(float2*)ptr = r;
}

// ---------------------------------------------------------------------------
// Causal flash attention v3, fp32.
// v2 -> v3: micro-tile 4q x 2k -> 4q x 4k (16 FMA per 32B LDS read instead of
// 8 per 24B) to flip the inner loop from LDS-read-bound to VALU-bound.
// 256 threads (16 tx x 16 ty), tile 64q x 64k.
// Balance kept: block handles q-tile PAIR (qt, 31-qt) = exactly 33 kv-tiles.
// Grid (16,32) = 512 blocks = 2/CU co-resident. K/V reg-prefetch kept.
// LDS rows padded to 68 floats (52,224 B -> up to 3 blocks/CU LDS-wise).
// ---------------------------------------------------------------------------
__global__ __launch_bounds__(256) void attn_fp32_v3(
    const float* __restrict__ Q, const float* __restrict__ K,
    const float* __restrict__ V, float* __restrict__ O)
{
    __shared__ float Qs[64][68];   // [d][q]
    __shared__ float KP[64][68];   // [d][k] for K, then [k][q] for P
    __shared__ float Vs[64][68];   // [k][d]

    int tid = threadIdx.x;
    int tx = tid & 15;        // k (or d) group of 4
    int ty = tid >> 4;        // 0..15, q group of 4
    int bh = blockIdx.y;
    int b = bh >> 4, h = bh & 15;

    const float* Qb = Q + (size_t)b * SS * D_MODEL + h * DK;
    const float* Kb = K + (size_t)b * SS * D_MODEL + h * DK;
    const float* Vb = V + (size_t)b * SS * D_MODEL + h * DK;
    float* Ob = O + (size_t)b * SS * D_MODEL + h * DK;

    // staging map: 256 threads x 4 iters cover 64 rows x 16 float4-cols
    int sr = tid >> 4;          // 0..15
    int sc = (tid & 15) << 2;   // 0,4,...,60

#pragma unroll 1
    for (int half = 0; half < 2; ++half) {
        int qt = half ? (31 - blockIdx.x) : blockIdx.x;
        int q0 = qt * 64;

        // Q stage (made visible by barrier #2 of first kv-tile)
#pragma unroll
        for (int u = 0; u < 4; ++u) {
            int r = u * 16 + sr;
            float4 qv = *(const float4*)(Qb + (size_t)(q0 + r) * D_MODEL + sc);
            Qs[sc + 0][r] = qv.x; Qs[sc + 1][r] = qv.y; Qs[sc + 2][r] = qv.z; Qs[sc + 3][r] = qv.w;
        }

        float m[4], l[4], o_[4][4];
#pragma unroll
        for (int i = 0; i < 4; i++) {
            m[i] = -1e30f; l[i] = 0.0f;
#pragma unroll
            for (int j = 0; j < 4; j++) o_[i][j] = 0.0f;
        }

        // prefetch kt=0
        float4 kv[4], vv[4];
#pragma unroll
        for (int u = 0; u < 4; ++u) {
            int r = u * 16 + sr;
            kv[u] = *(const float4*)(Kb + (size_t)r * D_MODEL + sc);
            vv[u] = *(const float4*)(Vb + (size_t)r * D_MODEL + sc);
        }

        for (int kt = 0; kt <= qt; ++kt) {
            __syncthreads();   // #1: prev tile's PV reads (Vs, KP-as-P) done
#pragma unroll
            for (int u = 0; u < 4; ++u) {
                int r = u * 16 + sr;
                KP[sc + 0][r] = kv[u].x; KP[sc + 1][r] = kv[u].y; KP[sc + 2][r] = kv[u].z; KP[sc + 3][r] = kv[u].w;
                *(float4*)&Vs[r][sc] = vv[u];
            }
            __syncthreads();   // #2: staging (and Q-stage) visible

            // prefetch next tile during compute
            if (kt < qt) {
                int k0n = (kt + 1) * 64;
#pragma unroll
                for (int u = 0; u < 4; ++u) {
                    int r = u * 16 + sr;
                    kv[u] = *(const float4*)(Kb + (size_t)(k0n + r) * D_MODEL + sc);
                    vv[u] = *(const float4*)(Vb + (size_t)(k0n + r) * D_MODEL + sc);
                }
            }

            // S = Q K^T: thread owns q-rows ty*4..+3, k-cols tx*4..+3
            float s[4][4];
#pragma unroll
            for (int i = 0; i < 4; i++)
#pragma unroll
                for (int j = 0; j < 4; j++) s[i][j] = 0.0f;
#pragma unroll 8
            for (int d = 0; d < 64; ++d) {
                float4 qa = *(const float4*)&Qs[d][ty * 4];
                float4 ka = *(const float4*)&KP[d][tx * 4];
                float qv4[4] = {qa.x, qa.y, qa.z, qa.w};
                float kv4[4] = {ka.x, ka.y, ka.z, ka.w};
#pragma unroll
                for (int i = 0; i < 4; i++)
#pragma unroll
                    for (int j = 0; j < 4; j++)
                        s[i][j] = fmaf(qv4[i], kv4[j], s[i][j]);
            }

            const float sc2 = 0.125f;   // 1/sqrt(64)
            if (kt == qt) {
#pragma unroll
                for (int i = 0; i < 4; i++)
#pragma unroll
                    for (int j = 0; j < 4; j++)
                        s[i][j] = (tx * 4 + j <= ty * 4 + i) ? s[i][j] * sc2 : -1e30f;
            } else {
#pragma unroll
                for (int i = 0; i < 4; i++)
#pragma unroll
                    for (int j = 0; j < 4; j++)
                        s[i][j] *= sc2;
            }

            // online softmax over the 16-lane tx group
            float p[4][4];
#pragma unroll
            for (int i = 0; i < 4; i++) {
                float rm = fmaxf(fmaxf(s[i][0], s[i][1]), fmaxf(s[i][2], s[i][3]));
                rm = fmaxf(rm, __shfl_xor(rm, 1));
                rm = fmaxf(rm, __shfl_xor(rm, 2));
                rm = fmaxf(rm, __shfl_xor(rm, 4));
                rm = fmaxf(rm, __shfl_xor(rm, 8));
                float nm = fmaxf(m[i], rm);
                float alpha = __expf(m[i] - nm);
                m[i] = nm;
                float rs = 0.0f;
#pragma unroll
                for (int j = 0; j < 4; j++) { p[i][j] = __expf(s[i][j] - nm); rs += p[i][j]; }
                rs += __shfl_xor(rs, 1);
                rs += __shfl_xor(rs, 2);
                rs += __shfl_xor(rs, 4);
                rs += __shfl_xor(rs, 8);
                l[i] = l[i] * alpha + rs;
#pragma unroll
                for (int j = 0; j < 4; j++) o_[i][j] *= alpha;
            }

            __syncthreads();   // #3: all S-phase reads of KP done
#pragma unroll
            for (int j = 0; j < 4; j++) {
                float4 pv = make_float4(p[0][j], p[1][j], p[2][j], p[3][j]);
                *(float4*)&KP[tx * 4 + j][ty * 4] = pv;   // P[k][q]
            }
            __syncthreads();   // #4: P visible

            // O += P V: thread owns q-rows ty*4..+3, d-cols tx*4..+3
#pragma unroll 8
            for (int k = 0; k < 64; ++k) {
                float4 pa = *(const float4*)&KP[k][ty * 4];
                float4 va = *(const float4*)&Vs[k][tx * 4];
                float pv4[4] = {pa.x, pa.y, pa.z, pa.w};
                float vv4[4] = {va.x, va.y, va.z, va.w};
#pragma unroll
                for (int i = 0; i < 4; i++)
#pragma unroll
                    for (int j = 0; j < 4; j++)
                        o_[i][j] = fmaf(pv4[i], vv4[j], o_[i][j]);
            }
        }

        // epilogue
#pragma unroll
        for (int i = 0; i < 4; i++) {
            float inv = 1.0f / l[i];
            float4 ov = make_float4(o_[i][0] * inv, o_[i][1] * inv, o_[i][2] * inv, o_[i][3] * inv);
            *(float4*)(Ob + (size_t)(q0 + ty * 4 + i) * D_MODEL + tx * 4) = ov;
        }
    }
}

// ---------------------------------------------------------------------------
extern "C" void kernel_launch(void* const* d_in, const int* in_sizes, int n_in,
                              void* d_out, int out_size, void* d_ws, size_t ws_size,
                              hipStream_t stream)
{
    const float* x    = (const float*)d_in[0];
    const int*   tpos = (const int*)d_in[1];
    const float* Wq   = (const float*)d_in[2];
    const float* Wk   = (const float*)d_in[3];
    const float* Wv   = (const float*)d_in[4];
    const float* Wo   = (const float*)d_in[5];
    float* out = (float*)d_out;

    float* ws = (float*)d_ws;
    float* q   = ws;                               // 4M floats
    float* k   = q + (size_t)MT * D_MODEL;         // 4M
    float* v   = k + (size_t)MT * D_MODEL;         // 4M
    float* o   = v + (size_t)MT * D_MODEL;         // 4M
    float* tab = o + (size_t)MT * D_MODEL;         // 2048*64 floats

    // 1. RoPE cos/sin table
    hipLaunchKernelGGL(rope_table_kernel, dim3(256), dim3(256), 0, stream, tab);
    // 2. Q/K/V projections
    hipLaunchKernelGGL(gemm_awt, dim3(16, 32, 3), dim3(256), 0, stream,
                       x, Wq, Wk, Wv, q, k, v);
    // 3. RoPE on Q and K in place
    hipLaunchKernelGGL(rope_apply_kernel, dim3(8192, 2), dim3(256), 0, stream,
                       q, k, tpos, tab);
    // 4. causal flash attention v3 (paired q-tiles, 256 threads, 4x4 micro)
    hipLaunchKernelGGL(attn_fp32_v3, dim3(16, 32), dim3(256), 0, stream,
                       q, k, v, o);
    // 5. output projection
    hipLaunchKernelGGL(gemm_awt, dim3(16, 32, 1), dim3(256), 0, stream,
                       o, Wo, Wo, Wo, out, out, out);
}

// Round 11
// 552.485 us; speedup vs baseline: 2.0361x; 1.6177x over previous
//
#include <hip/hip_runtime.h>
#include <math.h>

#define D_MODEL 1024
#define NHEADS  16
#define DK      64
#define BB      2
#define SS      2048
#define MT      (BB*SS)   // 4096 rows

typedef _Float16 half8 __attribute__((ext_vector_type(8)));
typedef _Float16 half4 __attribute__((ext_vector_type(4)));
typedef float f32x4 __attribute__((ext_vector_type(4)));

// ---------------------------------------------------------------------------
// RoPE table (unchanged)
// ---------------------------------------------------------------------------
__global__ void rope_table_kernel(float* __restrict__ tab) {
    int idx = blockIdx.x * 256 + threadIdx.x;
    int p = idx >> 5;
    int i = idx & 31;
    float freq = powf(10000.0f, -(float)(2 * i) / 64.0f);
    float ang = (float)p * freq;
    tab[p * 64 + i]      = cosf(ang);
    tab[p * 64 + 32 + i] = sinf(ang);
}

// ---------------------------------------------------------------------------
// f16-MFMA GEMM: C[m][n] = sum_k A[m][k] * W[n][k], fp32 in / fp32 out,
// f16 operands staged in LDS (converted on the fly), fp32 MFMA accumulate.
// Tile 128(M) x 64(N), BK=32, 256 threads = 4 waves (2x2 wave grid, each
// wave 64x32 via 4x2 fragments of mfma_f32_16x16x32_f16).
// Fragment layout (m89-verified): A lane l -> A[m=l&15][k=(l>>4)*8+j];
// B lane l -> W[n=l&15][k=(l>>4)*8+j]; D lane l reg r -> C[(l>>4)*4+r][l&15].
// LDS rows padded to 40 f16 (80B) -> b128 frag reads 16B-aligned, ~2-4 way.
// ---------------------------------------------------------------------------
__global__ __launch_bounds__(256) void gemm_awt_f16(
    const float* __restrict__ A,
    const float* __restrict__ W0, const float* __restrict__ W1, const float* __restrict__ W2,
    float* __restrict__ C0, float* __restrict__ C1, float* __restrict__ C2)
{
    const float* W;
    float* C;
    if (blockIdx.z == 0)      { W = W0; C = C0; }
    else if (blockIdx.z == 1) { W = W1; C = C1; }
    else                      { W = W2; C = C2; }

    __shared__ __align__(16) _Float16 Ah[128][40];
    __shared__ __align__(16) _Float16 Wh[64][40];

    int tid = threadIdx.x;
    int m0 = blockIdx.y * 128;
    int n0 = blockIdx.x * 64;

    int wid  = tid >> 6;
    int lane = tid & 63;
    int lm   = lane & 15;          // fragment row (m or n)
    int lk   = (lane >> 4) * 8;    // fragment k-offset
    int wm   = (wid & 1) * 64;     // wave m-offset
    int wn   = (wid >> 1) * 32;    // wave n-offset

    // staging map: thread -> (row, 16-float half of BK=32)
    int ar = tid >> 1;             // 0..127
    int ah = (tid & 1) * 16;       // 0 or 16

    const float* ApBase = A + (size_t)(m0 + ar) * D_MODEL + ah;
    const float* WpBase = W + (size_t)(n0 + (ar & 63)) * D_MODEL + ah;   // valid for tid<128

    f32x4 acc[4][2];
#pragma unroll
    for (int fm = 0; fm < 4; ++fm)
#pragma unroll
        for (int fn = 0; fn < 2; ++fn)
            acc[fm][fn] = (f32x4){0.f, 0.f, 0.f, 0.f};

    // prefetch k-step 0
    float4 ra[4], rw[4];
#pragma unroll
    for (int u = 0; u < 4; ++u) ra[u] = *(const float4*)(ApBase + u * 4);
    if (tid < 128) {
#pragma unroll
        for (int u = 0; u < 4; ++u) rw[u] = *(const float4*)(WpBase + u * 4);
    }

    for (int ks = 0; ks < 32; ++ks) {
        __syncthreads();   // previous iteration's fragment reads done
#pragma unroll
        for (int u = 0; u < 4; ++u) {
            float4 v = ra[u];
            half4 hv = {(_Float16)v.x, (_Float16)v.y, (_Float16)v.z, (_Float16)v.w};
            *(half4*)&Ah[ar][ah + u * 4] = hv;
        }
        if (tid < 128) {
#pragma unroll
            for (int u = 0; u < 4; ++u) {
                float4 v = rw[u];
                half4 hv = {(_Float16)v.x, (_Float16)v.y, (_Float16)v.z, (_Float16)v.w};
                *(half4*)&Wh[ar][ah + u * 4] = hv;
            }
        }
        __syncthreads();   // staging visible

        // prefetch next k-step during compute
        if (ks < 31) {
            int k0n = (ks + 1) * 32;
#pragma unroll
            for (int u = 0; u < 4; ++u) ra[u] = *(const float4*)(ApBase + k0n + u * 4);
            if (tid < 128) {
#pragma unroll
                for (int u = 0; u < 4; ++u) rw[u] = *(const float4*)(WpBase + k0n + u * 4);
            }
        }

        half8 af[4], bf[2];
#pragma unroll
        for (int fm = 0; fm < 4; ++fm) af[fm] = *(half8*)&Ah[wm + fm * 16 + lm][lk];
#pragma unroll
        for (int fn = 0; fn < 2; ++fn) bf[fn] = *(half8*)&Wh[wn + fn * 16 + lm][lk];
#pragma unroll
        for (int fm = 0; fm < 4; ++fm)
#pragma unroll
            for (int fn = 0; fn < 2; ++fn)
                acc[fm][fn] = __builtin_amdgcn_mfma_f32_16x16x32_f16(af[fm], bf[fn], acc[fm][fn], 0, 0, 0);
    }

    // epilogue: D lane l reg r -> C[row = (l>>4)*4 + r][col = l&15]
    int fq = lane >> 4, fr = lane & 15;
#pragma unroll
    for (int fm = 0; fm < 4; ++fm)
#pragma unroll
        for (int fn = 0; fn < 2; ++fn) {
            float* Cp = C + (size_t)(m0 + wm + fm * 16 + fq * 4) * D_MODEL + n0 + wn + fn * 16 + fr;
#pragma unroll
            for (int r = 0; r < 4; ++r)
                Cp[(size_t)r * D_MODEL] = acc[fm][fn][r];
        }
}

// ---------------------------------------------------------------------------
// RoPE apply (unchanged)
// ---------------------------------------------------------------------------
__global__ void rope_apply_kernel(float* __restrict__ Qp, float* __restrict__ Kp,
                                  const int* __restrict__ pos, const float* __restrict__ tab)
{
    int idx = blockIdx.x * 256 + threadIdx.x;
    float* base = blockIdx.y ? Kp : Qp;
    int i = idx & 31;
    int row = idx >> 5;
    float* ptr = base + (size_t)row * 64 + 2 * i;
    int p = pos[idx >> 9];
    float c  = tab[p * 64 + i];
    float sn = tab[p * 64 + 32 + i];
    float2 v = *(float2*)ptr;
    float2 r;
    r.x = v.x * c - v.y * sn;
    r.y = v.x * sn + v.y * c;
    *(float2*)ptr = r;
}

// ---------------------------------------------------------------------------
// Causal flash attention v3 (unchanged from round 10)
// ---------------------------------------------------------------------------
__global__ __launch_bounds__(256) void attn_fp32_v3(
    const float* __restrict__ Q, const float* __restrict__ K,
    const float* __restrict__ V, float* __restrict__ O)
{
    __shared__ float Qs[64][68];   // [d][q]
    __shared__ float KP[64][68];   // [d][k] for K, then [k][q] for P
    __shared__ float Vs[64][68];   // [k][d]

    int tid = threadIdx.x;
    int tx = tid & 15;
    int ty = tid >> 4;
    int bh = blockIdx.y;
    int b = bh >> 4, h = bh & 15;

    const float* Qb = Q + (size_t)b * SS * D_MODEL + h * DK;
    const float* Kb = K + (size_t)b * SS * D_MODEL + h * DK;
    const float* Vb = V + (size_t)b * SS * D_MODEL + h * DK;
    float* Ob = O + (size_t)b * SS * D_MODEL + h * DK;

    int sr = tid >> 4;
    int sc = (tid & 15) << 2;

#pragma unroll 1
    for (int half = 0; half < 2; ++half) {
        int qt = half ? (31 - blockIdx.x) : blockIdx.x;
        int q0 = qt * 64;

#pragma unroll
        for (int u = 0; u < 4; ++u) {
            int r = u * 16 + sr;
            float4 qv = *(const float4*)(Qb + (size_t)(q0 + r) * D_MODEL + sc);
            Qs[sc + 0][r] = qv.x; Qs[sc + 1][r] = qv.y; Qs[sc + 2][r] = qv.z; Qs[sc + 3][r] = qv.w;
        }

        float m[4], l[4], o_[4][4];
#pragma unroll
        for (int i = 0; i < 4; i++) {
            m[i] = -1e30f; l[i] = 0.0f;
#pragma unroll
            for (int j = 0; j < 4; j++) o_[i][j] = 0.0f;
        }

        float4 kv[4], vv[4];
#pragma unroll
        for (int u = 0; u < 4; ++u) {
            int r = u * 16 + sr;
            kv[u] = *(const float4*)(Kb + (size_t)r * D_MODEL + sc);
            vv[u] = *(const float4*)(Vb + (size_t)r * D_MODEL + sc);
        }

        for (int kt = 0; kt <= qt; ++kt) {
            __syncthreads();
#pragma unroll
            for (int u = 0; u < 4; ++u) {
                int r = u * 16 + sr;
                KP[sc + 0][r] = kv[u].x; KP[sc + 1][r] = kv[u].y; KP[sc + 2][r] = kv[u].z; KP[sc + 3][r] = kv[u].w;
                *(float4*)&Vs[r][sc] = vv[u];
            }
            __syncthreads();

            if (kt < qt) {
                int k0n = (kt + 1) * 64;
#pragma unroll
                for (int u = 0; u < 4; ++u) {
                    int r = u * 16 + sr;
                    kv[u] = *(const float4*)(Kb + (size_t)(k0n + r) * D_MODEL + sc);
                    vv[u] = *(const float4*)(Vb + (size_t)(k0n + r) * D_MODEL + sc);
                }
            }

            float s[4][4];
#pragma unroll
            for (int i = 0; i < 4; i++)
#pragma unroll
                for (int j = 0; j < 4; j++) s[i][j] = 0.0f;
#pragma unroll 8
            for (int d = 0; d < 64; ++d) {
                float4 qa = *(const float4*)&Qs[d][ty * 4];
                float4 ka = *(const float4*)&KP[d][tx * 4];
                float qv4[4] = {qa.x, qa.y, qa.z, qa.w};
                float kv4[4] = {ka.x, ka.y, ka.z, ka.w};
#pragma unroll
                for (int i = 0; i < 4; i++)
#pragma unroll
                    for (int j = 0; j < 4; j++)
                        s[i][j] = fmaf(qv4[i], kv4[j], s[i][j]);
            }

            const float sc2 = 0.125f;
            if (kt == qt) {
#pragma unroll
                for (int i = 0; i < 4; i++)
#pragma unroll
                    for (int j = 0; j < 4; j++)
                        s[i][j] = (tx * 4 + j <= ty * 4 + i) ? s[i][j] * sc2 : -1e30f;
            } else {
#pragma unroll
                for (int i = 0; i < 4; i++)
#pragma unroll
                    for (int j = 0; j < 4; j++)
                        s[i][j] *= sc2;
            }

            float p[4][4];
#pragma unroll
            for (int i = 0; i < 4; i++) {
                float rm = fmaxf(fmaxf(s[i][0], s[i][1]), fmaxf(s[i][2], s[i][3]));
                rm = fmaxf(rm, __shfl_xor(rm, 1));
                rm = fmaxf(rm, __shfl_xor(rm, 2));
                rm = fmaxf(rm, __shfl_xor(rm, 4));
                rm = fmaxf(rm, __shfl_xor(rm, 8));
                float nm = fmaxf(m[i], rm);
                float alpha = __expf(m[i] - nm);
                m[i] = nm;
                float rs = 0.0f;
#pragma unroll
                for (int j = 0; j < 4; j++) { p[i][j] = __expf(s[i][j] - nm); rs += p[i][j]; }
                rs += __shfl_xor(rs, 1);
                rs += __shfl_xor(rs, 2);
                rs += __shfl_xor(rs, 4);
                rs += __shfl_xor(rs, 8);
                l[i] = l[i] * alpha + rs;
#pragma unroll
                for (int j = 0; j < 4; j++) o_[i][j] *= alpha;
            }

            __syncthreads();
#pragma unroll
            for (int j = 0; j < 4; j++) {
                float4 pv = make_float4(p[0][j], p[1][j], p[2][j], p[3][j]);
                *(float4*)&KP[tx * 4 + j][ty * 4] = pv;
            }
            __syncthreads();

#pragma unroll 8
            for (int k = 0; k < 64; ++k) {
                float4 pa = *(const float4*)&KP[k][ty * 4];
                float4 va = *(const float4*)&Vs[k][tx * 4];
                float pv4[4] = {pa.x, pa.y, pa.z, pa.w};
                float vv4[4] = {va.x, va.y, va.z, va.w};
#pragma unroll
                for (int i = 0; i < 4; i++)
#pragma unroll
                    for (int j = 0; j < 4; j++)
                        o_[i][j] = fmaf(pv4[i], vv4[j], o_[i][j]);
            }
        }

#pragma unroll
        for (int i = 0; i < 4; i++) {
            float inv = 1.0f / l[i];
            float4 ov = make_float4(o_[i][0] * inv, o_[i][1] * inv, o_[i][2] * inv, o_[i][3] * inv);
            *(float4*)(Ob + (size_t)(q0 + ty * 4 + i) * D_MODEL + tx * 4) = ov;
        }
    }
}

// ---------------------------------------------------------------------------
extern "C" void kernel_launch(void* const* d_in, const int* in_sizes, int n_in,
                              void* d_out, int out_size, void* d_ws, size_t ws_size,
                              hipStream_t stream)
{
    const float* x    = (const float*)d_in[0];
    const int*   tpos = (const int*)d_in[1];
    const float* Wq   = (const float*)d_in[2];
    const float* Wk   = (const float*)d_in[3];
    const float* Wv   = (const float*)d_in[4];
    const float* Wo   = (const float*)d_in[5];
    float* out = (float*)d_out;

    float* ws = (float*)d_ws;
    float* q   = ws;                               // 4M floats
    float* k   = q + (size_t)MT * D_MODEL;         // 4M
    float* v   = k + (size_t)MT * D_MODEL;         // 4M
    float* o   = v + (size_t)MT * D_MODEL;         // 4M
    float* tab = o + (size_t)MT * D_MODEL;         // 2048*64 floats

    // 1. RoPE cos/sin table
    hipLaunchKernelGGL(rope_table_kernel, dim3(256), dim3(256), 0, stream, tab);
    // 2. Q/K/V projections (f16 MFMA, fp32 accumulate)
    hipLaunchKernelGGL(gemm_awt_f16, dim3(16, 32, 3), dim3(256), 0, stream,
                       x, Wq, Wk, Wv, q, k, v);
    // 3. RoPE on Q and K in place
    hipLaunchKernelGGL(rope_apply_kernel, dim3(8192, 2), dim3(256), 0, stream,
                       q, k, tpos, tab);
    // 4. causal flash attention v3 (unchanged)
    hipLaunchKernelGGL(attn_fp32_v3, dim3(16, 32), dim3(256), 0, stream,
                       q, k, v, o);
    // 5. output projection (f16 MFMA)
    hipLaunchKernelGGL(gemm_awt_f16, dim3(16, 32, 1), dim3(256), 0, stream,
                       o, Wo, Wo, Wo, out, out, out);
}

// Round 12
// 305.612 us; speedup vs baseline: 3.6809x; 1.8078x over previous
//
#include <hip/hip_runtime.h>
#include <math.h>

#define D_MODEL 1024
#define NHEADS  16
#define DK      64
#define BB      2
#define SS      2048
#define MT      (BB*SS)   // 4096 rows

typedef _Float16 half8 __attribute__((ext_vector_type(8)));
typedef _Float16 half4 __attribute__((ext_vector_type(4)));
typedef float f32x4 __attribute__((ext_vector_type(4)));

// ---------------------------------------------------------------------------
// RoPE table (unchanged)
// ---------------------------------------------------------------------------
__global__ void rope_table_kernel(float* __restrict__ tab) {
    int idx = blockIdx.x * 256 + threadIdx.x;
    int p = idx >> 5;
    int i = idx & 31;
    float freq = powf(10000.0f, -(float)(2 * i) / 64.0f);
    float ang = (float)p * freq;
    tab[p * 64 + i]      = cosf(ang);
    tab[p * 64 + 32 + i] = sinf(ang);
}

// ---------------------------------------------------------------------------
// f16-MFMA GEMM (unchanged from round-11, verified)
// ---------------------------------------------------------------------------
__global__ __launch_bounds__(256) void gemm_awt_f16(
    const float* __restrict__ A,
    const float* __restrict__ W0, const float* __restrict__ W1, const float* __restrict__ W2,
    float* __restrict__ C0, float* __restrict__ C1, float* __restrict__ C2)
{
    const float* W;
    float* C;
    if (blockIdx.z == 0)      { W = W0; C = C0; }
    else if (blockIdx.z == 1) { W = W1; C = C1; }
    else                      { W = W2; C = C2; }

    __shared__ __align__(16) _Float16 Ah[128][40];
    __shared__ __align__(16) _Float16 Wh[64][40];

    int tid = threadIdx.x;
    int m0 = blockIdx.y * 128;
    int n0 = blockIdx.x * 64;

    int wid  = tid >> 6;
    int lane = tid & 63;
    int lm   = lane & 15;
    int lk   = (lane >> 4) * 8;
    int wm   = (wid & 1) * 64;
    int wn   = (wid >> 1) * 32;

    int ar = tid >> 1;
    int ah = (tid & 1) * 16;

    const float* ApBase = A + (size_t)(m0 + ar) * D_MODEL + ah;
    const float* WpBase = W + (size_t)(n0 + (ar & 63)) * D_MODEL + ah;

    f32x4 acc[4][2];
#pragma unroll
    for (int fm = 0; fm < 4; ++fm)
#pragma unroll
        for (int fn = 0; fn < 2; ++fn)
            acc[fm][fn] = (f32x4){0.f, 0.f, 0.f, 0.f};

    float4 ra[4], rw[4];
#pragma unroll
    for (int u = 0; u < 4; ++u) ra[u] = *(const float4*)(ApBase + u * 4);
    if (tid < 128) {
#pragma unroll
        for (int u = 0; u < 4; ++u) rw[u] = *(const float4*)(WpBase + u * 4);
    }

    for (int ks = 0; ks < 32; ++ks) {
        __syncthreads();
#pragma unroll
        for (int u = 0; u < 4; ++u) {
            float4 v = ra[u];
            half4 hv = {(_Float16)v.x, (_Float16)v.y, (_Float16)v.z, (_Float16)v.w};
            *(half4*)&Ah[ar][ah + u * 4] = hv;
        }
        if (tid < 128) {
#pragma unroll
            for (int u = 0; u < 4; ++u) {
                float4 v = rw[u];
                half4 hv = {(_Float16)v.x, (_Float16)v.y, (_Float16)v.z, (_Float16)v.w};
                *(half4*)&Wh[ar][ah + u * 4] = hv;
            }
        }
        __syncthreads();

        if (ks < 31) {
            int k0n = (ks + 1) * 32;
#pragma unroll
            for (int u = 0; u < 4; ++u) ra[u] = *(const float4*)(ApBase + k0n + u * 4);
            if (tid < 128) {
#pragma unroll
                for (int u = 0; u < 4; ++u) rw[u] = *(const float4*)(WpBase + k0n + u * 4);
            }
        }

        half8 af[4], bf[2];
#pragma unroll
        for (int fm = 0; fm < 4; ++fm) af[fm] = *(half8*)&Ah[wm + fm * 16 + lm][lk];
#pragma unroll
        for (int fn = 0; fn < 2; ++fn) bf[fn] = *(half8*)&Wh[wn + fn * 16 + lm][lk];
#pragma unroll
        for (int fm = 0; fm < 4; ++fm)
#pragma unroll
            for (int fn = 0; fn < 2; ++fn)
                acc[fm][fn] = __builtin_amdgcn_mfma_f32_16x16x32_f16(af[fm], bf[fn], acc[fm][fn], 0, 0, 0);
    }

    int fq = lane >> 4, fr = lane & 15;
#pragma unroll
    for (int fm = 0; fm < 4; ++fm)
#pragma unroll
        for (int fn = 0; fn < 2; ++fn) {
            float* Cp = C + (size_t)(m0 + wm + fm * 16 + fq * 4) * D_MODEL + n0 + wn + fn * 16 + fr;
#pragma unroll
            for (int r = 0; r < 4; ++r)
                Cp[(size_t)r * D_MODEL] = acc[fm][fn][r];
        }
}

// ---------------------------------------------------------------------------
// RoPE apply (unchanged)
// ---------------------------------------------------------------------------
__global__ void rope_apply_kernel(float* __restrict__ Qp, float* __restrict__ Kp,
                                  const int* __restrict__ pos, const float* __restrict__ tab)
{
    int idx = blockIdx.x * 256 + threadIdx.x;
    float* base = blockIdx.y ? Kp : Qp;
    int i = idx & 31;
    int row = idx >> 5;
    float* ptr = base + (size_t)row * 64 + 2 * i;
    int p = pos[idx >> 9];
    float c  = tab[p * 64 + i];
    float sn = tab[p * 64 + 32 + i];
    float2 v = *(float2*)ptr;
    float2 r;
    r.x = v.x * c - v.y * sn;
    r.y = v.x * sn + v.y * c;
    *(float2*)ptr = r;
}

// ---------------------------------------------------------------------------
// Causal flash attention v4: f16 MFMA for QK^T and PV, fp32 accumulate,
// fp32 online softmax. 256 threads = 4 waves; wave owns 16 q-rows of the
// 64q x 64k tile. Q fragments in registers. Pairing (qt, 31-qt) kept.
// LDS: Kh[k][d] (f16, pad 72), Vt[d][k] (transposed, f16), Ph[q][k] (f16,
// wave-private rows -> no barrier between P-write and PV-read).
// Fragment maps identical to gemm_awt_f16 (verified round 11):
//   A-op: lane l -> X[p=l&15][c=(l>>4)*8+j]; B-op: lane l -> Y[n=l&15][c=...]
//   D: lane l reg r -> D[row=(l>>4)*4+r][col=l&15]
// ---------------------------------------------------------------------------
__global__ __launch_bounds__(256) void attn_mfma_f16(
    const float* __restrict__ Q, const float* __restrict__ K,
    const float* __restrict__ V, float* __restrict__ O)
{
    __shared__ __align__(16) _Float16 Kh[64][72];   // [k][d]
    __shared__ __align__(16) _Float16 Vt[64][72];   // [d][k]  (V transposed)
    __shared__ __align__(16) _Float16 Ph[64][72];   // [q][k]  (wave-private rows)

    int tid = threadIdx.x;
    int wid = tid >> 6;
    int lane = tid & 63;
    int fr = lane & 15;
    int fq = lane >> 4;
    int qbase = wid * 16;          // wave's q-rows within 64-tile

    int bh = blockIdx.y;
    int b = bh >> 4, h = bh & 15;

    const float* Qb = Q + (size_t)b * SS * D_MODEL + h * DK;
    const float* Kb = K + (size_t)b * SS * D_MODEL + h * DK;
    const float* Vb = V + (size_t)b * SS * D_MODEL + h * DK;
    float* Ob = O + (size_t)b * SS * D_MODEL + h * DK;

    // staging map: 256 threads x 4 iters cover 64 rows x 16 float4-cols
    int sr = tid >> 4;            // 0..15
    int sc4 = (tid & 15) << 2;    // 0,4,...,60

#pragma unroll 1
    for (int half = 0; half < 2; ++half) {
        int qt = half ? (31 - blockIdx.x) : blockIdx.x;
        int q0 = qt * 64;

        // Q fragments -> registers (row = q0+qbase+fr, k-offset ks*32+fq*8)
        half8 qf[2];
#pragma unroll
        for (int ks = 0; ks < 2; ++ks) {
            const float* qp = Qb + (size_t)(q0 + qbase + fr) * D_MODEL + ks * 32 + fq * 8;
            float4 a = *(const float4*)qp;
            float4 b2 = *(const float4*)(qp + 4);
            qf[ks] = (half8){(_Float16)a.x, (_Float16)a.y, (_Float16)a.z, (_Float16)a.w,
                             (_Float16)b2.x, (_Float16)b2.y, (_Float16)b2.z, (_Float16)b2.w};
        }

        float m[4], l[4];
        f32x4 oacc[4];                 // [d-frag]; lane reg r -> O[qbase+fq*4+r][fn*16+fr]
#pragma unroll
        for (int r = 0; r < 4; ++r) { m[r] = -1e30f; l[r] = 0.0f; }
#pragma unroll
        for (int fn = 0; fn < 4; ++fn) oacc[fn] = (f32x4){0.f, 0.f, 0.f, 0.f};

        // prefetch kt=0
        float4 kv[4], vv[4];
#pragma unroll
        for (int u = 0; u < 4; ++u) {
            int r = u * 16 + sr;
            kv[u] = *(const float4*)(Kb + (size_t)r * D_MODEL + sc4);
            vv[u] = *(const float4*)(Vb + (size_t)r * D_MODEL + sc4);
        }

        for (int kt = 0; kt <= qt; ++kt) {
            __syncthreads();   // #1: prev tile's Kh/Vt fragment reads done (all waves)
#pragma unroll
            for (int u = 0; u < 4; ++u) {
                int r = u * 16 + sr;
                float4 k4 = kv[u];
                *(half4*)&Kh[r][sc4] = (half4){(_Float16)k4.x, (_Float16)k4.y, (_Float16)k4.z, (_Float16)k4.w};
                float4 v4 = vv[u];
                Vt[sc4 + 0][r] = (_Float16)v4.x;
                Vt[sc4 + 1][r] = (_Float16)v4.y;
                Vt[sc4 + 2][r] = (_Float16)v4.z;
                Vt[sc4 + 3][r] = (_Float16)v4.w;
            }
            __syncthreads();   // #2: staging visible

            // prefetch next tile during compute
            if (kt < qt) {
                int k0n = (kt + 1) * 64;
#pragma unroll
                for (int u = 0; u < 4; ++u) {
                    int r = u * 16 + sr;
                    kv[u] = *(const float4*)(Kb + (size_t)(k0n + r) * D_MODEL + sc4);
                    vv[u] = *(const float4*)(Vb + (size_t)(k0n + r) * D_MODEL + sc4);
                }
            }

            // S = Q K^T : sacc[fn] -> S[qbase+fq*4+r][fn*16+fr]
            f32x4 sacc[4];
#pragma unroll
            for (int fn = 0; fn < 4; ++fn) sacc[fn] = (f32x4){0.f, 0.f, 0.f, 0.f};
#pragma unroll
            for (int ks = 0; ks < 2; ++ks) {
#pragma unroll
                for (int fn = 0; fn < 4; ++fn) {
                    half8 kf = *(half8*)&Kh[fn * 16 + fr][ks * 32 + fq * 8];
                    sacc[fn] = __builtin_amdgcn_mfma_f32_16x16x32_f16(qf[ks], kf, sacc[fn], 0, 0, 0);
                }
            }

            // scale + causal mask
            const float sc2 = 0.125f;   // 1/sqrt(64)
            float sv[4][4];             // [fn][r]
#pragma unroll
            for (int fn = 0; fn < 4; ++fn)
#pragma unroll
                for (int r = 0; r < 4; ++r) sv[fn][r] = sacc[fn][r] * sc2;
            if (kt == qt) {
#pragma unroll
                for (int fn = 0; fn < 4; ++fn)
#pragma unroll
                    for (int r = 0; r < 4; ++r)
                        if (fn * 16 + fr > qbase + fq * 4 + r) sv[fn][r] = -1e30f;
            }

            // online softmax (rows = qbase+fq*4+r; reduce across 16 fr-lanes)
            float p[4][4];              // [fn][r]
#pragma unroll
            for (int r = 0; r < 4; ++r) {
                float rm = fmaxf(fmaxf(sv[0][r], sv[1][r]), fmaxf(sv[2][r], sv[3][r]));
                rm = fmaxf(rm, __shfl_xor(rm, 1));
                rm = fmaxf(rm, __shfl_xor(rm, 2));
                rm = fmaxf(rm, __shfl_xor(rm, 4));
                rm = fmaxf(rm, __shfl_xor(rm, 8));
                float nm = fmaxf(m[r], rm);
                float alpha = __expf(m[r] - nm);
                m[r] = nm;
                float rs = 0.0f;
#pragma unroll
                for (int fn = 0; fn < 4; ++fn) { p[fn][r] = __expf(sv[fn][r] - nm); rs += p[fn][r]; }
                rs += __shfl_xor(rs, 1);
                rs += __shfl_xor(rs, 2);
                rs += __shfl_xor(rs, 4);
                rs += __shfl_xor(rs, 8);
                l[r] = l[r] * alpha + rs;
#pragma unroll
                for (int fn = 0; fn < 4; ++fn) oacc[fn][r] *= alpha;
            }

            // P -> f16 -> LDS (wave-private rows; in-wave lgkmcnt orders W->R)
#pragma unroll
            for (int r = 0; r < 4; ++r)
#pragma unroll
                for (int fn = 0; fn < 4; ++fn)
                    Ph[qbase + fq * 4 + r][fn * 16 + fr] = (_Float16)p[fn][r];

            // O += P V : A-op = P rows (own wave's rows), B-op = V^T rows
#pragma unroll
            for (int ks = 0; ks < 2; ++ks) {
                half8 pa = *(half8*)&Ph[qbase + fr][ks * 32 + fq * 8];
#pragma unroll
                for (int fn = 0; fn < 4; ++fn) {
                    half8 vb = *(half8*)&Vt[fn * 16 + fr][ks * 32 + fq * 8];
                    oacc[fn] = __builtin_amdgcn_mfma_f32_16x16x32_f16(pa, vb, oacc[fn], 0, 0, 0);
                }
            }
        }

        // epilogue: O[q0+qbase+fq*4+r][fn*16+fr] = oacc[fn][r] / l[r]
#pragma unroll
        for (int r = 0; r < 4; ++r) {
            float inv = 1.0f / l[r];
            size_t rowoff = (size_t)(q0 + qbase + fq * 4 + r) * D_MODEL;
#pragma unroll
            for (int fn = 0; fn < 4; ++fn)
                Ob[rowoff + fn * 16 + fr] = oacc[fn][r] * inv;
        }
    }
}

// ---------------------------------------------------------------------------
extern "C" void kernel_launch(void* const* d_in, const int* in_sizes, int n_in,
                              void* d_out, int out_size, void* d_ws, size_t ws_size,
                              hipStream_t stream)
{
    const float* x    = (const float*)d_in[0];
    const int*   tpos = (const int*)d_in[1];
    const float* Wq   = (const float*)d_in[2];
    const float* Wk   = (const float*)d_in[3];
    const float* Wv   = (const float*)d_in[4];
    const float* Wo   = (const float*)d_in[5];
    float* out = (float*)d_out;

    float* ws = (float*)d_ws;
    float* q   = ws;                               // 4M floats
    float* k   = q + (size_t)MT * D_MODEL;         // 4M
    float* v   = k + (size_t)MT * D_MODEL;         // 4M
    float* o   = v + (size_t)MT * D_MODEL;         // 4M
    float* tab = o + (size_t)MT * D_MODEL;         // 2048*64 floats

    // 1. RoPE cos/sin table
    hipLaunchKernelGGL(rope_table_kernel, dim3(256), dim3(256), 0, stream, tab);
    // 2. Q/K/V projections (f16 MFMA)
    hipLaunchKernelGGL(gemm_awt_f16, dim3(16, 32, 3), dim3(256), 0, stream,
                       x, Wq, Wk, Wv, q, k, v);
    // 3. RoPE on Q and K in place
    hipLaunchKernelGGL(rope_apply_kernel, dim3(8192, 2), dim3(256), 0, stream,
                       q, k, tpos, tab);
    // 4. causal flash attention v4 (f16 MFMA)
    hipLaunchKernelGGL(attn_mfma_f16, dim3(16, 32), dim3(256), 0, stream,
                       q, k, v, o);
    // 5. output projection (f16 MFMA)
    hipLaunchKernelGGL(gemm_awt_f16, dim3(16, 32, 1), dim3(256), 0, stream,
                       o, Wo, Wo, Wo, out, out, out);
}

// Round 13
// 255.165 us; speedup vs baseline: 4.4086x; 1.1977x over previous
//
#include <hip/hip_runtime.h>
#include <math.h>

#define D_MODEL 1024
#define NHEADS  16
#define DK      64
#define BB      2
#define SS      2048
#define MT      (BB*SS)   // 4096 rows

typedef _Float16 half8 __attribute__((ext_vector_type(8)));
typedef _Float16 half4 __attribute__((ext_vector_type(4)));
typedef float f32x4 __attribute__((ext_vector_type(4)));

// ---------------------------------------------------------------------------
// RoPE table (unchanged)
// ---------------------------------------------------------------------------
__global__ void rope_table_kernel(float* __restrict__ tab) {
    int idx = blockIdx.x * 256 + threadIdx.x;
    int p = idx >> 5;
    int i = idx & 31;
    float freq = powf(10000.0f, -(float)(2 * i) / 64.0f);
    float ang = (float)p * freq;
    tab[p * 64 + i]      = cosf(ang);
    tab[p * 64 + 32 + i] = sinf(ang);
}

// ---------------------------------------------------------------------------
// One-shot f32 -> f16 convert: x (4M elems) and Wq|Wk|Wv|Wo (1M each).
// 8 elems/thread. Same rounding as the old per-k-step staging converts.
// ---------------------------------------------------------------------------
__global__ __launch_bounds__(256) void cvt_f16_kernel(
    const float* __restrict__ x,
    const float* __restrict__ Wq, const float* __restrict__ Wk,
    const float* __restrict__ Wv, const float* __restrict__ Wo,
    _Float16* __restrict__ xh, _Float16* __restrict__ wh)
{
    size_t idx8 = ((size_t)blockIdx.x * 256 + threadIdx.x) * 8;
    const float* src;
    _Float16* dst;
    if (idx8 < (size_t)4194304) {               // x: 4M elems
        src = x + idx8;
        dst = xh + idx8;
    } else {
        size_t r = idx8 - 4194304;
        int wi = (int)(r >> 20);                // each W: 2^20 elems
        size_t off = r & 1048575;
        src = (wi == 0 ? Wq : wi == 1 ? Wk : wi == 2 ? Wv : Wo) + off;
        dst = wh + ((size_t)wi << 20) + off;
    }
    float4 a = *(const float4*)src;
    float4 b = *(const float4*)(src + 4);
    half8 h = {(_Float16)a.x, (_Float16)a.y, (_Float16)a.z, (_Float16)a.w,
               (_Float16)b.x, (_Float16)b.y, (_Float16)b.z, (_Float16)b.w};
    *(half8*)dst = h;
}

// ---------------------------------------------------------------------------
// Pure-f16 MFMA GEMM: C[m][n] = sum_k A[m][k] * W[n][k], f16 in / f32 out.
// Tile 128(M) x 64(N), BK=64, 256 threads = 4 waves (2x2), wave = 64x32
// via 4x2 fragments x 2 k-chunks of mfma_f32_16x16x32_f16.
// LDS rows padded to 72 f16 (144B) -> frag-read stride 36 dwords -> 2-way
// bank aliasing (free, m136). Reg-prefetch double buffer, 2 barriers/step.
// Fragment maps identical to the round-11-verified kernel.
// ---------------------------------------------------------------------------
__global__ __launch_bounds__(256) void gemm_h(
    const _Float16* __restrict__ A,
    const _Float16* __restrict__ W0, const _Float16* __restrict__ W1, const _Float16* __restrict__ W2,
    float* __restrict__ C0, float* __restrict__ C1, float* __restrict__ C2)
{
    const _Float16* W;
    float* C;
    if (blockIdx.z == 0)      { W = W0; C = C0; }
    else if (blockIdx.z == 1) { W = W1; C = C1; }
    else                      { W = W2; C = C2; }

    __shared__ __align__(16) _Float16 Ah[128][72];
    __shared__ __align__(16) _Float16 Wh2[64][72];

    int tid = threadIdx.x;
    int m0 = blockIdx.y * 128;
    int n0 = blockIdx.x * 64;

    int wid  = tid >> 6;
    int lane = tid & 63;
    int lm   = lane & 15;
    int lk   = (lane >> 4) * 8;
    int wm   = (wid & 1) * 64;
    int wn   = (wid >> 1) * 32;

    // staging maps
    int ar = tid >> 1;             // A: 0..127, 2 thr/row, 32 f16 each
    int ac = (tid & 1) * 32;
    int wr = tid >> 2;             // W: 0..63, 4 thr/row, 16 f16 each
    int wc = (tid & 3) * 16;

    const _Float16* Ap = A + (size_t)(m0 + ar) * D_MODEL + ac;
    const _Float16* Wp = W + (size_t)(n0 + wr) * D_MODEL + wc;

    f32x4 acc[4][2];
#pragma unroll
    for (int fm = 0; fm < 4; ++fm)
#pragma unroll
        for (int fn = 0; fn < 2; ++fn)
            acc[fm][fn] = (f32x4){0.f, 0.f, 0.f, 0.f};

    // prefetch k-step 0
    half8 ra[4], rw[2];
#pragma unroll
    for (int u = 0; u < 4; ++u) ra[u] = *(const half8*)(Ap + u * 8);
#pragma unroll
    for (int u = 0; u < 2; ++u) rw[u] = *(const half8*)(Wp + u * 8);

    for (int ks = 0; ks < 16; ++ks) {
        __syncthreads();   // previous iteration's fragment reads done
#pragma unroll
        for (int u = 0; u < 4; ++u) *(half8*)&Ah[ar][ac + u * 8] = ra[u];
#pragma unroll
        for (int u = 0; u < 2; ++u) *(half8*)&Wh2[wr][wc + u * 8] = rw[u];
        __syncthreads();   // staging visible

        if (ks < 15) {
            int k0n = (ks + 1) * 64;
#pragma unroll
            for (int u = 0; u < 4; ++u) ra[u] = *(const half8*)(Ap + k0n + u * 8);
#pragma unroll
            for (int u = 0; u < 2; ++u) rw[u] = *(const half8*)(Wp + k0n + u * 8);
        }

#pragma unroll
        for (int kk = 0; kk < 2; ++kk) {
            half8 af[4], bf[2];
#pragma unroll
            for (int fm = 0; fm < 4; ++fm) af[fm] = *(half8*)&Ah[wm + fm * 16 + lm][kk * 32 + lk];
#pragma unroll
            for (int fn = 0; fn < 2; ++fn) bf[fn] = *(half8*)&Wh2[wn + fn * 16 + lm][kk * 32 + lk];
#pragma unroll
            for (int fm = 0; fm < 4; ++fm)
#pragma unroll
                for (int fn = 0; fn < 2; ++fn)
                    acc[fm][fn] = __builtin_amdgcn_mfma_f32_16x16x32_f16(af[fm], bf[fn], acc[fm][fn], 0, 0, 0);
        }
    }

    // epilogue: D lane l reg r -> C[row=(l>>4)*4+r][col=l&15]
    int fq = lane >> 4, fr = lane & 15;
#pragma unroll
    for (int fm = 0; fm < 4; ++fm)
#pragma unroll
        for (int fn = 0; fn < 2; ++fn) {
            float* Cp = C + (size_t)(m0 + wm + fm * 16 + fq * 4) * D_MODEL + n0 + wn + fn * 16 + fr;
#pragma unroll
            for (int r = 0; r < 4; ++r)
                Cp[(size_t)r * D_MODEL] = acc[fm][fn][r];
        }
}

// ---------------------------------------------------------------------------
// RoPE apply (unchanged, f32 q/k)
// ---------------------------------------------------------------------------
__global__ void rope_apply_kernel(float* __restrict__ Qp, float* __restrict__ Kp,
                                  const int* __restrict__ pos, const float* __restrict__ tab)
{
    int idx = blockIdx.x * 256 + threadIdx.x;
    float* base = blockIdx.y ? Kp : Qp;
    int i = idx & 31;
    int row = idx >> 5;
    float* ptr = base + (size_t)row * 64 + 2 * i;
    int p = pos[idx >> 9];
    float c  = tab[p * 64 + i];
    float sn = tab[p * 64 + 32 + i];
    float2 v = *(float2*)ptr;
    float2 r;
    r.x = v.x * c - v.y * sn;
    r.y = v.x * sn + v.y * c;
    *(float2*)ptr = r;
}

// ---------------------------------------------------------------------------
// Causal flash attention v4 (round-12 verified), one change: O written as f16
// (same rounding point as the old O-proj staging convert -> identical values).
// ---------------------------------------------------------------------------
__global__ __launch_bounds__(256) void attn_mfma_f16(
    const float* __restrict__ Q, const float* __restrict__ K,
    const float* __restrict__ V, _Float16* __restrict__ O)
{
    __shared__ __align__(16) _Float16 Kh[64][72];   // [k][d]
    __shared__ __align__(16) _Float16 Vt[64][72];   // [d][k]
    __shared__ __align__(16) _Float16 Ph[64][72];   // [q][k] wave-private rows

    int tid = threadIdx.x;
    int wid = tid >> 6;
    int lane = tid & 63;
    int fr = lane & 15;
    int fq = lane >> 4;
    int qbase = wid * 16;

    int bh = blockIdx.y;
    int b = bh >> 4, h = bh & 15;

    const float* Qb = Q + (size_t)b * SS * D_MODEL + h * DK;
    const float* Kb = K + (size_t)b * SS * D_MODEL + h * DK;
    const float* Vb = V + (size_t)b * SS * D_MODEL + h * DK;
    _Float16* Ob = O + (size_t)b * SS * D_MODEL + h * DK;

    int sr = tid >> 4;
    int sc4 = (tid & 15) << 2;

#pragma unroll 1
    for (int half = 0; half < 2; ++half) {
        int qt = half ? (31 - blockIdx.x) : blockIdx.x;
        int q0 = qt * 64;

        half8 qf[2];
#pragma unroll
        for (int ks = 0; ks < 2; ++ks) {
            const float* qp = Qb + (size_t)(q0 + qbase + fr) * D_MODEL + ks * 32 + fq * 8;
            float4 a = *(const float4*)qp;
            float4 b2 = *(const float4*)(qp + 4);
            qf[ks] = (half8){(_Float16)a.x, (_Float16)a.y, (_Float16)a.z, (_Float16)a.w,
                             (_Float16)b2.x, (_Float16)b2.y, (_Float16)b2.z, (_Float16)b2.w};
        }

        float m[4], l[4];
        f32x4 oacc[4];
#pragma unroll
        for (int r = 0; r < 4; ++r) { m[r] = -1e30f; l[r] = 0.0f; }
#pragma unroll
        for (int fn = 0; fn < 4; ++fn) oacc[fn] = (f32x4){0.f, 0.f, 0.f, 0.f};

        float4 kv[4], vv[4];
#pragma unroll
        for (int u = 0; u < 4; ++u) {
            int r = u * 16 + sr;
            kv[u] = *(const float4*)(Kb + (size_t)r * D_MODEL + sc4);
            vv[u] = *(const float4*)(Vb + (size_t)r * D_MODEL + sc4);
        }

        for (int kt = 0; kt <= qt; ++kt) {
            __syncthreads();
#pragma unroll
            for (int u = 0; u < 4; ++u) {
                int r = u * 16 + sr;
                float4 k4 = kv[u];
                *(half4*)&Kh[r][sc4] = (half4){(_Float16)k4.x, (_Float16)k4.y, (_Float16)k4.z, (_Float16)k4.w};
                float4 v4 = vv[u];
                Vt[sc4 + 0][r] = (_Float16)v4.x;
                Vt[sc4 + 1][r] = (_Float16)v4.y;
                Vt[sc4 + 2][r] = (_Float16)v4.z;
                Vt[sc4 + 3][r] = (_Float16)v4.w;
            }
            __syncthreads();

            if (kt < qt) {
                int k0n = (kt + 1) * 64;
#pragma unroll
                for (int u = 0; u < 4; ++u) {
                    int r = u * 16 + sr;
                    kv[u] = *(const float4*)(Kb + (size_t)(k0n + r) * D_MODEL + sc4);
                    vv[u] = *(const float4*)(Vb + (size_t)(k0n + r) * D_MODEL + sc4);
                }
            }

            f32x4 sacc[4];
#pragma unroll
            for (int fn = 0; fn < 4; ++fn) sacc[fn] = (f32x4){0.f, 0.f, 0.f, 0.f};
#pragma unroll
            for (int ks = 0; ks < 2; ++ks) {
#pragma unroll
                for (int fn = 0; fn < 4; ++fn) {
                    half8 kf = *(half8*)&Kh[fn * 16 + fr][ks * 32 + fq * 8];
                    sacc[fn] = __builtin_amdgcn_mfma_f32_16x16x32_f16(qf[ks], kf, sacc[fn], 0, 0, 0);
                }
            }

            const float sc2 = 0.125f;
            float sv[4][4];
#pragma unroll
            for (int fn = 0; fn < 4; ++fn)
#pragma unroll
                for (int r = 0; r < 4; ++r) sv[fn][r] = sacc[fn][r] * sc2;
            if (kt == qt) {
#pragma unroll
                for (int fn = 0; fn < 4; ++fn)
#pragma unroll
                    for (int r = 0; r < 4; ++r)
                        if (fn * 16 + fr > qbase + fq * 4 + r) sv[fn][r] = -1e30f;
            }

            float p[4][4];
#pragma unroll
            for (int r = 0; r < 4; ++r) {
                float rm = fmaxf(fmaxf(sv[0][r], sv[1][r]), fmaxf(sv[2][r], sv[3][r]));
                rm = fmaxf(rm, __shfl_xor(rm, 1));
                rm = fmaxf(rm, __shfl_xor(rm, 2));
                rm = fmaxf(rm, __shfl_xor(rm, 4));
                rm = fmaxf(rm, __shfl_xor(rm, 8));
                float nm = fmaxf(m[r], rm);
                float alpha = __expf(m[r] - nm);
                m[r] = nm;
                float rs = 0.0f;
#pragma unroll
                for (int fn = 0; fn < 4; ++fn) { p[fn][r] = __expf(sv[fn][r] - nm); rs += p[fn][r]; }
                rs += __shfl_xor(rs, 1);
                rs += __shfl_xor(rs, 2);
                rs += __shfl_xor(rs, 4);
                rs += __shfl_xor(rs, 8);
                l[r] = l[r] * alpha + rs;
#pragma unroll
                for (int fn = 0; fn < 4; ++fn) oacc[fn][r] *= alpha;
            }

#pragma unroll
            for (int r = 0; r < 4; ++r)
#pragma unroll
                for (int fn = 0; fn < 4; ++fn)
                    Ph[qbase + fq * 4 + r][fn * 16 + fr] = (_Float16)p[fn][r];

#pragma unroll
            for (int ks = 0; ks < 2; ++ks) {
                half8 pa = *(half8*)&Ph[qbase + fr][ks * 32 + fq * 8];
#pragma unroll
                for (int fn = 0; fn < 4; ++fn) {
                    half8 vb = *(half8*)&Vt[fn * 16 + fr][ks * 32 + fq * 8];
                    oacc[fn] = __builtin_amdgcn_mfma_f32_16x16x32_f16(pa, vb, oacc[fn], 0, 0, 0);
                }
            }
        }

#pragma unroll
        for (int r = 0; r < 4; ++r) {
            float inv = 1.0f / l[r];
            size_t rowoff = (size_t)(q0 + qbase + fq * 4 + r) * D_MODEL;
#pragma unroll
            for (int fn = 0; fn < 4; ++fn)
                Ob[rowoff + fn * 16 + fr] = (_Float16)(oacc[fn][r] * inv);
        }
    }
}

// ---------------------------------------------------------------------------
extern "C" void kernel_launch(void* const* d_in, const int* in_sizes, int n_in,
                              void* d_out, int out_size, void* d_ws, size_t ws_size,
                              hipStream_t stream)
{
    const float* x    = (const float*)d_in[0];
    const int*   tpos = (const int*)d_in[1];
    const float* Wq   = (const float*)d_in[2];
    const float* Wk   = (const float*)d_in[3];
    const float* Wv   = (const float*)d_in[4];
    const float* Wo   = (const float*)d_in[5];
    float* out = (float*)d_out;

    // ws layout (64.5 MB, same budget as proven rounds):
    float* q = (float*)d_ws;                       // 4M f32
    float* k = q + (size_t)MT * D_MODEL;           // 4M f32
    float* v = k + (size_t)MT * D_MODEL;           // 4M f32
    _Float16* xoh = (_Float16*)(v + (size_t)MT * D_MODEL);  // 4M f16: xh, later oh
    _Float16* wh  = xoh + (size_t)MT * D_MODEL;             // 4M f16: Wq|Wk|Wv|Wo
    float* tab = (float*)(wh + (size_t)MT * D_MODEL);       // 2048*64 f32

    // 1. f32->f16 one-shot convert (x + 4 weights)
    hipLaunchKernelGGL(cvt_f16_kernel, dim3(4096), dim3(256), 0, stream,
                       x, Wq, Wk, Wv, Wo, xoh, wh);
    // 2. RoPE cos/sin table
    hipLaunchKernelGGL(rope_table_kernel, dim3(256), dim3(256), 0, stream, tab);
    // 3. Q/K/V projections (pure-f16 GEMM, f32 out)
    hipLaunchKernelGGL(gemm_h, dim3(16, 32, 3), dim3(256), 0, stream,
                       xoh, wh, wh + (1u << 20), wh + (2u << 20), q, k, v);
    // 4. RoPE on Q and K in place (f32)
    hipLaunchKernelGGL(rope_apply_kernel, dim3(8192, 2), dim3(256), 0, stream,
                       q, k, tpos, tab);
    // 5. causal flash attention (writes O as f16 into xoh)
    hipLaunchKernelGGL(attn_mfma_f16, dim3(16, 32), dim3(256), 0, stream,
                       q, k, v, xoh);
    // 6. output projection (f16 GEMM, f32 out)
    hipLaunchKernelGGL(gemm_h, dim3(16, 32, 1), dim3(256), 0, stream,
                       xoh, wh + (3u << 20), wh + (3u << 20), wh + (3u << 20),
                       out, out, out);
}